// Round 1
// baseline (452.814 us; speedup 1.0000x reference)
//
#include <hip/hip_runtime.h>
#include <math.h>

#define N_USER 100000
#define N_ITEM 50000
#define N_EDGE 800000
#define D_IN 256
#define D_H 128
#define HEADS 4

// ---------------------------------------------------------------------------
// CSR row offsets from a sorted dst index array: rs[i] = lower_bound(dst, i)
// ---------------------------------------------------------------------------
__global__ void row_offsets_kernel(const int* __restrict__ dst, int n_edge,
                                   int* __restrict__ rs, int n_dst) {
  int i = blockIdx.x * blockDim.x + threadIdx.x;
  if (i > n_dst) return;
  int lo = 0, hi = n_edge;
  while (lo < hi) {
    int mid = (lo + hi) >> 1;
    if (dst[mid] < i) lo = mid + 1; else hi = mid;
  }
  rs[i] = lo;
}

// ---------------------------------------------------------------------------
// C[N,128] = A[N,256] @ W[256,128] + bias   (fp32 vector GEMM)
// block = 256 threads, tile 64 rows x 128 cols, K-step 32, 8x4 micro-tile
// ---------------------------------------------------------------------------
__global__ __launch_bounds__(256) void gemm_proj_kernel(
    const float* __restrict__ A, const float* __restrict__ W,
    const float* __restrict__ bias, float* __restrict__ C, int N) {
  __shared__ float As[32][68];   // transposed [k][row], row stride 272B (16B-aligned)
  __shared__ float Ws[32][128];  // [k][col]
  const int t = threadIdx.x;
  const int tx = t & 31, ty = t >> 5;
  const int r0 = ty * 8, c0 = tx * 4;
  const int brow = blockIdx.x * 64;
  float acc[8][4];
#pragma unroll
  for (int r = 0; r < 8; ++r)
#pragma unroll
    for (int c = 0; c < 4; ++c) acc[r][c] = 0.f;

  for (int k0 = 0; k0 < D_IN; k0 += 32) {
#pragma unroll
    for (int i = 0; i < 2; ++i) {             // A tile: 64x32 = 512 float4
      int idx = t * 2 + i;
      int row = idx >> 3, k4 = (idx & 7) << 2;
      float4 av = make_float4(0.f, 0.f, 0.f, 0.f);
      int gr = brow + row;
      if (gr < N) av = *(const float4*)&A[(size_t)gr * D_IN + k0 + k4];
      As[k4 + 0][row] = av.x; As[k4 + 1][row] = av.y;
      As[k4 + 2][row] = av.z; As[k4 + 3][row] = av.w;
    }
#pragma unroll
    for (int i = 0; i < 4; ++i) {             // W tile: 32x128 = 1024 float4
      int idx = t * 4 + i;
      int wk = idx >> 5, c4 = (idx & 31) << 2;
      *(float4*)&Ws[wk][c4] = *(const float4*)&W[(size_t)(k0 + wk) * D_H + c4];
    }
    __syncthreads();
#pragma unroll
    for (int k = 0; k < 32; ++k) {
      float4 b4 = *(const float4*)&Ws[k][c0];
      float4 a0 = *(const float4*)&As[k][r0];
      float4 a1 = *(const float4*)&As[k][r0 + 4];
      float ar[8] = {a0.x, a0.y, a0.z, a0.w, a1.x, a1.y, a1.z, a1.w};
      float br[4] = {b4.x, b4.y, b4.z, b4.w};
#pragma unroll
      for (int r = 0; r < 8; ++r)
#pragma unroll
        for (int c = 0; c < 4; ++c) acc[r][c] = fmaf(ar[r], br[c], acc[r][c]);
    }
    __syncthreads();
  }
  float4 bv = *(const float4*)&bias[c0];
#pragma unroll
  for (int r = 0; r < 8; ++r) {
    int gr = brow + r0 + r;
    if (gr < N) {
      float4 o = make_float4(acc[r][0] + bv.x, acc[r][1] + bv.y,
                             acc[r][2] + bv.z, acc[r][3] + bv.w);
      *(float4*)&C[(size_t)gr * D_H + c0] = o;
    }
  }
}

// ---------------------------------------------------------------------------
// s[n,4] = C[n,128] @ a[4,128]^T  (one wave per row; optional second a)
// ---------------------------------------------------------------------------
__global__ __launch_bounds__(256) void scores_kernel(
    const float* __restrict__ C, int n,
    const float* __restrict__ a0, float* __restrict__ s0,
    const float* __restrict__ a1, float* __restrict__ s1) {
  int wid = (blockIdx.x * blockDim.x + threadIdx.x) >> 6;
  int lane = threadIdx.x & 63;
  if (wid >= n) return;
  float2 v = *(const float2*)&C[(size_t)wid * D_H + lane * 2];
#pragma unroll
  for (int h = 0; h < HEADS; ++h) {
    float p = v.x * a0[h * D_H + lane * 2] + v.y * a0[h * D_H + lane * 2 + 1];
#pragma unroll
    for (int off = 32; off; off >>= 1) p += __shfl_xor(p, off);
    if (lane == 0) s0[wid * HEADS + h] = p;
  }
  if (a1) {
#pragma unroll
    for (int h = 0; h < HEADS; ++h) {
      float p = v.x * a1[h * D_H + lane * 2] + v.y * a1[h * D_H + lane * 2 + 1];
#pragma unroll
      for (int off = 32; off; off >>= 1) p += __shfl_xor(p, off);
      if (lane == 0) s1[wid * HEADS + h] = p;
    }
  }
}

// ---------------------------------------------------------------------------
// One wave per dst node: online segment softmax + attention-weighted sum.
// lane owns 2 of the 128 dims. Optionally fuses s_out = out @ a_next^T.
// ---------------------------------------------------------------------------
__global__ __launch_bounds__(256) void attend_kernel(
    const float* __restrict__ h_src, const float* __restrict__ s_src,
    const float* __restrict__ s_dst, const int* __restrict__ src_idx,
    const int* __restrict__ rs, float* __restrict__ out, int n_dst,
    const float* __restrict__ a_next, float* __restrict__ s_out) {
  int wid = (blockIdx.x * blockDim.x + threadIdx.x) >> 6;
  int lane = threadIdx.x & 63;
  if (wid >= n_dst) return;
  int e0 = rs[wid], e1 = rs[wid + 1];
  float sd[HEADS];
#pragma unroll
  for (int h = 0; h < HEADS; ++h) sd[h] = s_dst[wid * HEADS + h];
  float m[HEADS], den[HEADS], acc0[HEADS], acc1[HEADS];
#pragma unroll
  for (int h = 0; h < HEADS; ++h) {
    m[h] = -INFINITY; den[h] = 0.f; acc0[h] = 0.f; acc1[h] = 0.f;
  }
  for (int base = e0; base < e1; base += 64) {
    int e = base + lane;
    int s = (e < e1) ? src_idx[e] : 0;
    float lg[HEADS], w[HEADS];
#pragma unroll
    for (int h = 0; h < HEADS; ++h) {
      float v = s_src[s * HEADS + h] + sd[h];
      v = (v >= 0.f) ? v : 0.2f * v;           // leaky_relu(0.2)
      lg[h] = (e < e1) ? v : -INFINITY;
    }
#pragma unroll
    for (int h = 0; h < HEADS; ++h) {
      float cm = lg[h];
#pragma unroll
      for (int off = 32; off; off >>= 1) cm = fmaxf(cm, __shfl_xor(cm, off));
      float mn = fmaxf(m[h], cm);
      float r = __expf(m[h] - mn);             // m=-inf -> r=0 on first chunk
      w[h] = __expf(lg[h] - mn);               // invalid lanes: exp(-inf)=0
      float ws = w[h];
#pragma unroll
      for (int off = 32; off; off >>= 1) ws += __shfl_xor(ws, off);
      den[h] = den[h] * r + ws;
      acc0[h] *= r; acc1[h] *= r;
      m[h] = mn;
    }
    int cnt = min(64, e1 - base);
    for (int j = 0; j < cnt; ++j) {
      int sj = __shfl(s, j);
      float2 hv = *(const float2*)&h_src[(size_t)sj * D_H + lane * 2];
#pragma unroll
      for (int h = 0; h < HEADS; ++h) {
        float wj = __shfl(w[h], j);
        acc0[h] = fmaf(wj, hv.x, acc0[h]);
        acc1[h] = fmaf(wj, hv.y, acc1[h]);
      }
    }
  }
  float o0 = 0.f, o1 = 0.f;
#pragma unroll
  for (int h = 0; h < HEADS; ++h) {
    if (den[h] > 0.f) {
      float v0 = acc0[h] / den[h], v1 = acc1[h] / den[h];
      v0 = (v0 > 0.f) ? v0 : expm1f(v0);       // elu
      v1 = (v1 > 0.f) ? v1 : expm1f(v1);
      o0 += v0; o1 += v1;
    }
  }
  o0 *= 0.25f; o1 *= 0.25f;                    // mean over 4 heads
  *(float2*)&out[(size_t)wid * D_H + lane * 2] = make_float2(o0, o1);
  if (s_out) {                                  // fused next-layer src scores
#pragma unroll
    for (int h = 0; h < HEADS; ++h) {
      float p = o0 * a_next[h * D_H + lane * 2] + o1 * a_next[h * D_H + lane * 2 + 1];
#pragma unroll
      for (int off = 32; off; off >>= 1) p += __shfl_xor(p, off);
      if (lane == 0) s_out[wid * HEADS + h] = p;
    }
  }
}

// ---------------------------------------------------------------------------
extern "C" void kernel_launch(void* const* d_in, const int* in_sizes, int n_in,
                              void* d_out, int out_size, void* d_ws, size_t ws_size,
                              hipStream_t stream) {
  const float* h_user     = (const float*)d_in[0];
  const float* h_item     = (const float*)d_in[1];
  const float* w_user     = (const float*)d_in[2];
  const float* b_user     = (const float*)d_in[3];
  const float* w_item     = (const float*)d_in[4];
  const float* b_item     = (const float*)d_in[5];
  const float* a_user_src = (const float*)d_in[6];
  const float* a_user_dst = (const float*)d_in[7];
  const float* a_item_src = (const float*)d_in[8];
  const float* a_item_dst = (const float*)d_in[9];
  const int* i2u_src = (const int*)d_in[10];
  const int* i2u_dst = (const int*)d_in[11];
  const int* u2i_src = (const int*)d_in[12];
  const int* u2i_dst = (const int*)d_in[13];

  float* out_user = (float*)d_out;                       // hu_new (N_USER,128)
  float* out_item = out_user + (size_t)N_USER * D_H;     // hi_new (N_ITEM,128)

  // workspace layout (~82.3 MB)
  float* hu      = (float*)d_ws;                         // (N_USER,128)
  float* hi      = hu + (size_t)N_USER * D_H;            // (N_ITEM,128)
  float* s_i_src = hi + (size_t)N_ITEM * D_H;            // (N_ITEM,4) hi@a_user_src^T
  float* s_i_dst = s_i_src + (size_t)N_ITEM * HEADS;     // (N_ITEM,4) hi@a_item_dst^T
  float* s_u_dst = s_i_dst + (size_t)N_ITEM * HEADS;     // (N_USER,4) hu@a_user_dst^T
  float* s_un    = s_u_dst + (size_t)N_USER * HEADS;     // (N_USER,4) hu_new@a_item_src^T
  int* user_rs = (int*)(s_un + (size_t)N_USER * HEADS);  // N_USER+1
  int* item_rs = user_rs + (N_USER + 1);                 // N_ITEM+1

  // CSR offsets from the sorted dst arrays
  hipLaunchKernelGGL(row_offsets_kernel, dim3((N_USER + 1 + 255) / 256), dim3(256), 0,
                     stream, i2u_dst, N_EDGE, user_rs, N_USER);
  hipLaunchKernelGGL(row_offsets_kernel, dim3((N_ITEM + 1 + 255) / 256), dim3(256), 0,
                     stream, u2i_dst, N_EDGE, item_rs, N_ITEM);

  // projections
  hipLaunchKernelGGL(gemm_proj_kernel, dim3((N_USER + 63) / 64), dim3(256), 0, stream,
                     h_user, w_user, b_user, hu, N_USER);
  hipLaunchKernelGGL(gemm_proj_kernel, dim3((N_ITEM + 63) / 64), dim3(256), 0, stream,
                     h_item, w_item, b_item, hi, N_ITEM);

  // per-node attention scores
  hipLaunchKernelGGL(scores_kernel, dim3(N_ITEM / 4), dim3(256), 0, stream,
                     hi, N_ITEM, a_user_src, s_i_src, a_item_dst, s_i_dst);
  hipLaunchKernelGGL(scores_kernel, dim3(N_USER / 4), dim3(256), 0, stream,
                     hu, N_USER, a_user_dst, s_u_dst, (const float*)nullptr, (float*)nullptr);

  // layer 1: items -> users  (fuses hu_new @ a_item_src^T into s_un)
  hipLaunchKernelGGL(attend_kernel, dim3(N_USER / 4), dim3(256), 0, stream,
                     hi, s_i_src, s_u_dst, i2u_src, user_rs, out_user, N_USER,
                     a_item_src, s_un);
  // layer 2: updated users -> items
  hipLaunchKernelGGL(attend_kernel, dim3(N_ITEM / 4), dim3(256), 0, stream,
                     out_user, s_un, s_i_dst, u2i_src, item_rs, out_item, N_ITEM,
                     (const float*)nullptr, (float*)nullptr);
}

// Round 3
// 445.616 us; speedup vs baseline: 1.0162x; 1.0162x over previous
//
#include <hip/hip_runtime.h>
#include <math.h>

#define N_USER 100000
#define N_ITEM 50000
#define N_EDGE 800000
#define D_IN 256
#define D_H 128
#define HEADS 4

// ---------------------------------------------------------------------------
// CSR row offsets from a sorted dst index array: rs[i] = lower_bound(dst, i)
// ---------------------------------------------------------------------------
__global__ void row_offsets_kernel(const int* __restrict__ dst, int n_edge,
                                   int* __restrict__ rs, int n_dst) {
  int i = blockIdx.x * blockDim.x + threadIdx.x;
  if (i > n_dst) return;
  int lo = 0, hi = n_edge;
  while (lo < hi) {
    int mid = (lo + hi) >> 1;
    if (dst[mid] < i) lo = mid + 1; else hi = mid;
  }
  rs[i] = lo;
}

// ---------------------------------------------------------------------------
// C[N,128] = A[N,256] @ W[256,128] + bias   (fp32 vector GEMM)
// ---------------------------------------------------------------------------
__global__ __launch_bounds__(256) void gemm_proj_kernel(
    const float* __restrict__ A, const float* __restrict__ W,
    const float* __restrict__ bias, float* __restrict__ C, int N) {
  __shared__ float As[32][68];
  __shared__ float Ws[32][128];
  const int t = threadIdx.x;
  const int tx = t & 31, ty = t >> 5;
  const int r0 = ty * 8, c0 = tx * 4;
  const int brow = blockIdx.x * 64;
  float acc[8][4];
#pragma unroll
  for (int r = 0; r < 8; ++r)
#pragma unroll
    for (int c = 0; c < 4; ++c) acc[r][c] = 0.f;

  for (int k0 = 0; k0 < D_IN; k0 += 32) {
#pragma unroll
    for (int i = 0; i < 2; ++i) {
      int idx = t * 2 + i;
      int row = idx >> 3, k4 = (idx & 7) << 2;
      float4 av = make_float4(0.f, 0.f, 0.f, 0.f);
      int gr = brow + row;
      if (gr < N) av = *(const float4*)&A[(size_t)gr * D_IN + k0 + k4];
      As[k4 + 0][row] = av.x; As[k4 + 1][row] = av.y;
      As[k4 + 2][row] = av.z; As[k4 + 3][row] = av.w;
    }
#pragma unroll
    for (int i = 0; i < 4; ++i) {
      int idx = t * 4 + i;
      int wk = idx >> 5, c4 = (idx & 31) << 2;
      *(float4*)&Ws[wk][c4] = *(const float4*)&W[(size_t)(k0 + wk) * D_H + c4];
    }
    __syncthreads();
#pragma unroll
    for (int k = 0; k < 32; ++k) {
      float4 b4 = *(const float4*)&Ws[k][c0];
      float4 a0 = *(const float4*)&As[k][r0];
      float4 a1 = *(const float4*)&As[k][r0 + 4];
      float ar[8] = {a0.x, a0.y, a0.z, a0.w, a1.x, a1.y, a1.z, a1.w};
      float br[4] = {b4.x, b4.y, b4.z, b4.w};
#pragma unroll
      for (int r = 0; r < 8; ++r)
#pragma unroll
        for (int c = 0; c < 4; ++c) acc[r][c] = fmaf(ar[r], br[c], acc[r][c]);
    }
    __syncthreads();
  }
  float4 bv = *(const float4*)&bias[c0];
#pragma unroll
  for (int r = 0; r < 8; ++r) {
    int gr = brow + r0 + r;
    if (gr < N) {
      float4 o = make_float4(acc[r][0] + bv.x, acc[r][1] + bv.y,
                             acc[r][2] + bv.z, acc[r][3] + bv.w);
      *(float4*)&C[(size_t)gr * D_H + c0] = o;
    }
  }
}

// ---------------------------------------------------------------------------
// s[n,4] = C[n,128] @ a[4,128]^T  (one wave per row; optional second a)
// ---------------------------------------------------------------------------
__global__ __launch_bounds__(256) void scores_kernel(
    const float* __restrict__ C, int n,
    const float* __restrict__ a0, float* __restrict__ s0,
    const float* __restrict__ a1, float* __restrict__ s1) {
  int wid = (blockIdx.x * blockDim.x + threadIdx.x) >> 6;
  int lane = threadIdx.x & 63;
  if (wid >= n) return;
  float2 v = *(const float2*)&C[(size_t)wid * D_H + lane * 2];
#pragma unroll
  for (int h = 0; h < HEADS; ++h) {
    float p = v.x * a0[h * D_H + lane * 2] + v.y * a0[h * D_H + lane * 2 + 1];
#pragma unroll
    for (int off = 32; off; off >>= 1) p += __shfl_xor(p, off);
    if (lane == 0) s0[wid * HEADS + h] = p;
  }
  if (a1) {
#pragma unroll
    for (int h = 0; h < HEADS; ++h) {
      float p = v.x * a1[h * D_H + lane * 2] + v.y * a1[h * D_H + lane * 2 + 1];
#pragma unroll
      for (int off = 32; off; off >>= 1) p += __shfl_xor(p, off);
      if (lane == 0) s1[wid * HEADS + h] = p;
    }
  }
}

// ---------------------------------------------------------------------------
// Phase 1: per-edge logits (E x 4), edge-parallel, float4.
// ---------------------------------------------------------------------------
__global__ __launch_bounds__(256) void edge_logits_kernel(
    const float* __restrict__ s_src, const float* __restrict__ s_dst,
    const int* __restrict__ src_idx, const int* __restrict__ dst_idx,
    float* __restrict__ logit, int n_edge) {
  int e = blockIdx.x * blockDim.x + threadIdx.x;
  if (e >= n_edge) return;
  int s = src_idx[e], d = dst_idx[e];
  float4 a = *(const float4*)&s_src[(size_t)s * HEADS];
  float4 b = *(const float4*)&s_dst[(size_t)d * HEADS];
  float4 v = make_float4(a.x + b.x, a.y + b.y, a.z + b.z, a.w + b.w);
  v.x = (v.x >= 0.f) ? v.x : 0.2f * v.x;
  v.y = (v.y >= 0.f) ? v.y : 0.2f * v.y;
  v.z = (v.z >= 0.f) ? v.z : 0.2f * v.z;
  v.w = (v.w >= 0.f) ? v.w : 0.2f * v.w;
  *(float4*)&logit[(size_t)e * HEADS] = v;
}

// ---------------------------------------------------------------------------
// Phase 2: segment softmax stats, one thread per dst node.
// Rewrites logit[e] -> w[e] = exp(logit - m) in place; stores rden = 1/sum.
// ---------------------------------------------------------------------------
__global__ __launch_bounds__(256) void seg_softmax_kernel(
    const int* __restrict__ rs, float* __restrict__ logit,
    float* __restrict__ rden, int n_dst) {
  int i = blockIdx.x * blockDim.x + threadIdx.x;
  if (i >= n_dst) return;
  int e0 = rs[i], e1 = rs[i + 1];
  float4 m = make_float4(-INFINITY, -INFINITY, -INFINITY, -INFINITY);
  for (int e = e0; e < e1; ++e) {
    float4 lg = *(const float4*)&logit[(size_t)e * HEADS];
    m.x = fmaxf(m.x, lg.x); m.y = fmaxf(m.y, lg.y);
    m.z = fmaxf(m.z, lg.z); m.w = fmaxf(m.w, lg.w);
  }
  float4 den = make_float4(0.f, 0.f, 0.f, 0.f);
  for (int e = e0; e < e1; ++e) {
    float4 lg = *(const float4*)&logit[(size_t)e * HEADS];
    float4 w = make_float4(__expf(lg.x - m.x), __expf(lg.y - m.y),
                           __expf(lg.z - m.z), __expf(lg.w - m.w));
    den.x += w.x; den.y += w.y; den.z += w.z; den.w += w.w;
    *(float4*)&logit[(size_t)e * HEADS] = w;
  }
  float4 r;
  r.x = den.x > 0.f ? 1.f / den.x : 0.f;
  r.y = den.y > 0.f ? 1.f / den.y : 0.f;
  r.z = den.z > 0.f ? 1.f / den.z : 0.f;
  r.w = den.w > 0.f ? 1.f / den.w : 0.f;
  *(float4*)&rden[(size_t)i * HEADS] = r;
}

// ---------------------------------------------------------------------------
// Phase 3: weighted gather-sum. One wave per dst; lanes = 2 edge-slots x
// 32 dim-groups (float4). No cross-lane softmax; one half-merge at the end.
// Optionally fuses s_out = out @ a_next^T.
// ---------------------------------------------------------------------------
#define ACC4(acc, wv, hv) \
  acc.x = fmaf(wv, hv.x, acc.x); acc.y = fmaf(wv, hv.y, acc.y); \
  acc.z = fmaf(wv, hv.z, acc.z); acc.w = fmaf(wv, hv.w, acc.w);

__global__ __launch_bounds__(256) void attend_sum_kernel(
    const float* __restrict__ h_src, const float* __restrict__ w4,
    const float* __restrict__ rden, const int* __restrict__ src_idx,
    const int* __restrict__ rs, float* __restrict__ out, int n_dst,
    const float* __restrict__ a_next, float* __restrict__ s_out) {
  int wid = (blockIdx.x * blockDim.x + threadIdx.x) >> 6;
  int lane = threadIdx.x & 63;
  if (wid >= n_dst) return;
  const int el = lane >> 5;        // edge slot 0/1
  const int dl = lane & 31;        // dim group: dims [dl*4, dl*4+4)
  int e0 = rs[wid], e1 = rs[wid + 1];

  float4 acc0 = make_float4(0, 0, 0, 0), acc1 = acc0, acc2 = acc0, acc3 = acc0;

  int base = e0;
  for (; base + 4 <= e1; base += 4) {          // 4 edges per iteration
    int eA = base + el, eB = base + 2 + el;
    int sA = src_idx[eA], sB = src_idx[eB];
    float4 hA = *(const float4*)&h_src[(size_t)sA * D_H + dl * 4];
    float4 hB = *(const float4*)&h_src[(size_t)sB * D_H + dl * 4];
    float4 wA = *(const float4*)&w4[(size_t)eA * HEADS];
    float4 wB = *(const float4*)&w4[(size_t)eB * HEADS];
    ACC4(acc0, wA.x, hA); ACC4(acc1, wA.y, hA);
    ACC4(acc2, wA.z, hA); ACC4(acc3, wA.w, hA);
    ACC4(acc0, wB.x, hB); ACC4(acc1, wB.y, hB);
    ACC4(acc2, wB.z, hB); ACC4(acc3, wB.w, hB);
  }
  for (; base < e1; base += 2) {               // tail: up to 3 edges left
    int e = base + el;
    bool valid = e < e1;
    int ec = valid ? e : e1 - 1;
    int s = src_idx[ec];
    float4 hv = *(const float4*)&h_src[(size_t)s * D_H + dl * 4];
    float4 wv = *(const float4*)&w4[(size_t)ec * HEADS];
    if (!valid) wv = make_float4(0, 0, 0, 0);
    ACC4(acc0, wv.x, hv); ACC4(acc1, wv.y, hv);
    ACC4(acc2, wv.z, hv); ACC4(acc3, wv.w, hv);
  }

  // merge the two edge-slots (xor 32): both halves end with the full sum
#define MRG(a) \
  a.x += __shfl_xor(a.x, 32); a.y += __shfl_xor(a.y, 32); \
  a.z += __shfl_xor(a.z, 32); a.w += __shfl_xor(a.w, 32);
  MRG(acc0) MRG(acc1) MRG(acc2) MRG(acc3)
#undef MRG

  float4 r = *(const float4*)&rden[(size_t)wid * HEADS];
#define ELU4(a, rr) \
  a.x *= rr; a.y *= rr; a.z *= rr; a.w *= rr; \
  a.x = (a.x > 0.f) ? a.x : expm1f(a.x); \
  a.y = (a.y > 0.f) ? a.y : expm1f(a.y); \
  a.z = (a.z > 0.f) ? a.z : expm1f(a.z); \
  a.w = (a.w > 0.f) ? a.w : expm1f(a.w);
  ELU4(acc0, r.x) ELU4(acc1, r.y) ELU4(acc2, r.z) ELU4(acc3, r.w)
#undef ELU4

  float4 o = make_float4(0.25f * (acc0.x + acc1.x + acc2.x + acc3.x),
                         0.25f * (acc0.y + acc1.y + acc2.y + acc3.y),
                         0.25f * (acc0.z + acc1.z + acc2.z + acc3.z),
                         0.25f * (acc0.w + acc1.w + acc2.w + acc3.w));
  if (el == 0) *(float4*)&out[(size_t)wid * D_H + dl * 4] = o;

  if (s_out) {  // fused next-layer src scores: s_out[h] = sum_d o[d]*a_next[h][d]
#pragma unroll
    for (int h = 0; h < HEADS; ++h) {
      const float* ah = &a_next[h * D_H + dl * 4];
      float p = o.x * ah[0] + o.y * ah[1] + o.z * ah[2] + o.w * ah[3];
#pragma unroll
      for (int off = 16; off; off >>= 1) p += __shfl_xor(p, off);
      if (lane == 0) s_out[wid * HEADS + h] = p;
    }
  }
}
#undef ACC4

// ---------------------------------------------------------------------------
extern "C" void kernel_launch(void* const* d_in, const int* in_sizes, int n_in,
                              void* d_out, int out_size, void* d_ws, size_t ws_size,
                              hipStream_t stream) {
  const float* h_user     = (const float*)d_in[0];
  const float* h_item     = (const float*)d_in[1];
  const float* w_user     = (const float*)d_in[2];
  const float* b_user     = (const float*)d_in[3];
  const float* w_item     = (const float*)d_in[4];
  const float* b_item     = (const float*)d_in[5];
  const float* a_user_src = (const float*)d_in[6];
  const float* a_user_dst = (const float*)d_in[7];
  const float* a_item_src = (const float*)d_in[8];
  const float* a_item_dst = (const float*)d_in[9];
  const int* i2u_src = (const int*)d_in[10];
  const int* i2u_dst = (const int*)d_in[11];
  const int* u2i_src = (const int*)d_in[12];
  const int* u2i_dst = (const int*)d_in[13];

  float* out_user = (float*)d_out;                       // hu_new (N_USER,128)
  float* out_item = out_user + (size_t)N_USER * D_H;     // hi_new (N_ITEM,128)

  // workspace layout
  float* hu      = (float*)d_ws;                         // (N_USER,128) 51.2MB
  float* hi      = hu + (size_t)N_USER * D_H;            // (N_ITEM,128)
  float* s_i_src = hi + (size_t)N_ITEM * D_H;            // (N_ITEM,4)
  float* s_i_dst = s_i_src + (size_t)N_ITEM * HEADS;     // (N_ITEM,4)
  float* s_u_dst = s_i_dst + (size_t)N_ITEM * HEADS;     // (N_USER,4)
  float* s_un    = s_u_dst + (size_t)N_USER * HEADS;     // (N_USER,4)
  int* user_rs = (int*)(s_un + (size_t)N_USER * HEADS);  // N_USER+1
  int* item_rs = user_rs + (N_USER + 1);                 // N_ITEM+1
  // hu is dead after scores_kernel -> alias edge buffers into it
  float* logit  = hu;                                    // (E,4) 12.8MB
  float* rden_u = hu + (size_t)N_EDGE * HEADS;           // (N_USER,4)
  float* rden_i = rden_u + (size_t)N_USER * HEADS;       // (N_ITEM,4)

  // CSR offsets from the sorted dst arrays
  hipLaunchKernelGGL(row_offsets_kernel, dim3((N_USER + 1 + 255) / 256), dim3(256), 0,
                     stream, i2u_dst, N_EDGE, user_rs, N_USER);
  hipLaunchKernelGGL(row_offsets_kernel, dim3((N_ITEM + 1 + 255) / 256), dim3(256), 0,
                     stream, u2i_dst, N_EDGE, item_rs, N_ITEM);

  // projections
  hipLaunchKernelGGL(gemm_proj_kernel, dim3((N_USER + 63) / 64), dim3(256), 0, stream,
                     h_user, w_user, b_user, hu, N_USER);
  hipLaunchKernelGGL(gemm_proj_kernel, dim3((N_ITEM + 63) / 64), dim3(256), 0, stream,
                     h_item, w_item, b_item, hi, N_ITEM);

  // per-node attention scores
  hipLaunchKernelGGL(scores_kernel, dim3(N_ITEM / 4), dim3(256), 0, stream,
                     hi, N_ITEM, a_user_src, s_i_src, a_item_dst, s_i_dst);
  hipLaunchKernelGGL(scores_kernel, dim3(N_USER / 4), dim3(256), 0, stream,
                     hu, N_USER, a_user_dst, s_u_dst, (const float*)nullptr, (float*)nullptr);

  // ---- layer 1: items -> users ----
  hipLaunchKernelGGL(edge_logits_kernel, dim3((N_EDGE + 255) / 256), dim3(256), 0, stream,
                     s_i_src, s_u_dst, i2u_src, i2u_dst, logit, N_EDGE);
  hipLaunchKernelGGL(seg_softmax_kernel, dim3((N_USER + 255) / 256), dim3(256), 0, stream,
                     user_rs, logit, rden_u, N_USER);
  hipLaunchKernelGGL(attend_sum_kernel, dim3((N_USER + 3) / 4), dim3(256), 0, stream,
                     hi, logit, rden_u, i2u_src, user_rs, out_user, N_USER,
                     a_item_src, s_un);

  // ---- layer 2: updated users -> items ----
  hipLaunchKernelGGL(edge_logits_kernel, dim3((N_EDGE + 255) / 256), dim3(256), 0, stream,
                     s_un, s_i_dst, u2i_src, u2i_dst, logit, N_EDGE);
  hipLaunchKernelGGL(seg_softmax_kernel, dim3((N_ITEM + 255) / 256), dim3(256), 0, stream,
                     item_rs, logit, rden_i, N_ITEM);
  hipLaunchKernelGGL(attend_sum_kernel, dim3((N_ITEM + 3) / 4), dim3(256), 0, stream,
                     out_user, logit, rden_i, u2i_src, item_rs, out_item, N_ITEM,
                     (const float*)nullptr, (float*)nullptr);
}

// Round 4
// 415.694 us; speedup vs baseline: 1.0893x; 1.0720x over previous
//
#include <hip/hip_runtime.h>
#include <math.h>

#define N_USER 100000
#define N_ITEM 50000
#define N_EDGE 800000
#define D_IN 256
#define D_H 128
#define HEADS 4

typedef __attribute__((ext_vector_type(8))) short short8v;   // 8 bf16 (4 VGPR)
typedef __attribute__((ext_vector_type(4))) float f32x4;     // MFMA C/D

__device__ __forceinline__ unsigned short f2bf(float x) {    // RNE f32->bf16
  unsigned u = __float_as_uint(x);
  return (unsigned short)((u + 0x7FFFu + ((u >> 16) & 1u)) >> 16);
}
__device__ __forceinline__ float bf2f(unsigned short h) {
  return __uint_as_float((unsigned)h << 16);
}

// ---------------------------------------------------------------------------
// CSR row offsets from a sorted dst index array: rs[i] = lower_bound(dst, i)
// ---------------------------------------------------------------------------
__global__ void row_offsets_kernel(const int* __restrict__ dst, int n_edge,
                                   int* __restrict__ rs, int n_dst) {
  int i = blockIdx.x * blockDim.x + threadIdx.x;
  if (i > n_dst) return;
  int lo = 0, hi = n_edge;
  while (lo < hi) {
    int mid = (lo + hi) >> 1;
    if (dst[mid] < i) lo = mid + 1; else hi = mid;
  }
  rs[i] = lo;
}

// ---------------------------------------------------------------------------
// One-time W prep: W[256][128] fp32 -> Wt_hi/Wt_lo[128][256] bf16, with the
// within-32 k permutation pos(k) matching the MFMA fragment slot order, so the
// GEMM's LDS fragment reads are contiguous 16B. Slot (kb=lane>>4, j=0..7) maps
// k = kb*4 + (j&3) + 16*(j>>2); pos is its inverse laid out as kb*8 + j.
// ---------------------------------------------------------------------------
__global__ __launch_bounds__(256) void wt_prep_kernel(
    const float* __restrict__ W, unsigned short* __restrict__ WtHi,
    unsigned short* __restrict__ WtLo) {
  int tid = blockIdx.x * blockDim.x + threadIdx.x;     // 32768 = 256k x 128n
  if (tid >= D_IN * D_H) return;
  int n = tid & 127, k = tid >> 7;                     // consecutive tid -> coalesced W read
  float x = W[(size_t)k * D_H + n];
  unsigned short h = f2bf(x);
  unsigned short l = f2bf(x - bf2f(h));
  int kk = k & 31, kbase = k & ~31;
  int pos = (kk < 16) ? ((kk >> 2) * 8 + (kk & 3))
                      : (((kk - 16) >> 2) * 8 + 4 + (kk & 3));
  WtHi[(size_t)n * D_IN + kbase + pos] = h;
  WtLo[(size_t)n * D_IN + kbase + pos] = l;
}

// ---------------------------------------------------------------------------
// C[M,128] = A[M,256] @ W[256,128] + bias via split-bf16 MFMA (3 products:
// Ah*Wh + Ah*Wl + Al*Wh; fp32 accumulate ~ fp32 accuracy).
// Block: 256 thr = 4 waves; tile 128 rows x 128 cols; BK=32 (one k-frag).
// Wave w owns rows w*32..w*32+31 (2 m-frags x 8 n-frags of 16x16).
// C/D layout (verified): col = lane&15, row = (lane>>4)*4 + reg.
// ---------------------------------------------------------------------------
__global__ __launch_bounds__(256) void gemm_mfma_kernel(
    const float* __restrict__ A, const unsigned short* __restrict__ WtHi,
    const unsigned short* __restrict__ WtLo, const float* __restrict__ bias,
    float* __restrict__ C, int M) {
  __shared__ unsigned short Ah[128][32], Al[128][32];   // 8KB + 8KB
  __shared__ unsigned short Bh[128][32], Bl[128][32];   // [n][k-permuted] 8+8KB
  const int t = threadIdx.x;
  const int wave = t >> 6, lane = t & 63;
  const int l15 = lane & 15, kb = lane >> 4;
  const int m0 = blockIdx.x * 128;

  f32x4 acc[2][8];
#pragma unroll
  for (int mf = 0; mf < 2; ++mf)
#pragma unroll
    for (int nf = 0; nf < 8; ++nf) acc[mf][nf] = (f32x4){0.f, 0.f, 0.f, 0.f};

  for (int k0 = 0; k0 < D_IN; k0 += 32) {
    // stage A tile 128x32 fp32 -> hi/lo bf16, k permuted to slot order
#pragma unroll
    for (int i = 0; i < 4; ++i) {
      int idx = t + i * 256;             // 0..1023
      int row = idx >> 3, c = idx & 7;   // float4 chunk c: k-offset 4c
      float4 av = make_float4(0.f, 0.f, 0.f, 0.f);
      if (m0 + row < M) av = *(const float4*)&A[(size_t)(m0 + row) * D_IN + k0 + c * 4];
      ushort4 hv, lv;
      hv.x = f2bf(av.x); lv.x = f2bf(av.x - bf2f(hv.x));
      hv.y = f2bf(av.y); lv.y = f2bf(av.y - bf2f(hv.y));
      hv.z = f2bf(av.z); lv.z = f2bf(av.z - bf2f(hv.z));
      hv.w = f2bf(av.w); lv.w = f2bf(av.w - bf2f(hv.w));
      int base = (c < 4) ? c * 8 : (c - 4) * 8 + 4;   // slot-order position
      *(ushort4*)&Ah[row][base] = hv;
      *(ushort4*)&Al[row][base] = lv;
    }
    // stage B tile: Wt is already transposed+permuted -> straight 16B copies
#pragma unroll
    for (int i = 0; i < 2; ++i) {
      int idx = t + i * 256;             // 0..511
      int row = idx >> 2, ch = idx & 3;  // 4 x 16B per row (32 bf16)
      *(uint4*)&Bh[row][ch * 8] = *(const uint4*)&WtHi[(size_t)row * D_IN + k0 + ch * 8];
      *(uint4*)&Bl[row][ch * 8] = *(const uint4*)&WtLo[(size_t)row * D_IN + k0 + ch * 8];
    }
    __syncthreads();

    short8v ah[2], al[2];
#pragma unroll
    for (int mf = 0; mf < 2; ++mf) {
      ah[mf] = *(const short8v*)&Ah[wave * 32 + mf * 16 + l15][kb * 8];
      al[mf] = *(const short8v*)&Al[wave * 32 + mf * 16 + l15][kb * 8];
    }
#pragma unroll
    for (int nf = 0; nf < 8; ++nf) {
      short8v bh = *(const short8v*)&Bh[nf * 16 + l15][kb * 8];
      short8v bl = *(const short8v*)&Bl[nf * 16 + l15][kb * 8];
#pragma unroll
      for (int mf = 0; mf < 2; ++mf) {
        acc[mf][nf] = __builtin_amdgcn_mfma_f32_16x16x32_bf16(ah[mf], bh, acc[mf][nf], 0, 0, 0);
        acc[mf][nf] = __builtin_amdgcn_mfma_f32_16x16x32_bf16(ah[mf], bl, acc[mf][nf], 0, 0, 0);
        acc[mf][nf] = __builtin_amdgcn_mfma_f32_16x16x32_bf16(al[mf], bh, acc[mf][nf], 0, 0, 0);
      }
    }
    __syncthreads();
  }

#pragma unroll
  for (int nf = 0; nf < 8; ++nf) {
    float bv = bias[nf * 16 + l15];
#pragma unroll
    for (int mf = 0; mf < 2; ++mf) {
#pragma unroll
      for (int r = 0; r < 4; ++r) {
        int grow = m0 + wave * 32 + mf * 16 + kb * 4 + r;
        if (grow < M) C[(size_t)grow * D_H + nf * 16 + l15] = acc[mf][nf][r] + bv;
      }
    }
  }
}

// ---------------------------------------------------------------------------
// s[n,4] = C[n,128] @ a[4,128]^T  (one wave per row; optional second a)
// ---------------------------------------------------------------------------
__global__ __launch_bounds__(256) void scores_kernel(
    const float* __restrict__ C, int n,
    const float* __restrict__ a0, float* __restrict__ s0,
    const float* __restrict__ a1, float* __restrict__ s1) {
  int wid = (blockIdx.x * blockDim.x + threadIdx.x) >> 6;
  int lane = threadIdx.x & 63;
  if (wid >= n) return;
  float2 v = *(const float2*)&C[(size_t)wid * D_H + lane * 2];
#pragma unroll
  for (int h = 0; h < HEADS; ++h) {
    float p = v.x * a0[h * D_H + lane * 2] + v.y * a0[h * D_H + lane * 2 + 1];
#pragma unroll
    for (int off = 32; off; off >>= 1) p += __shfl_xor(p, off);
    if (lane == 0) s0[wid * HEADS + h] = p;
  }
  if (a1) {
#pragma unroll
    for (int h = 0; h < HEADS; ++h) {
      float p = v.x * a1[h * D_H + lane * 2] + v.y * a1[h * D_H + lane * 2 + 1];
#pragma unroll
      for (int off = 32; off; off >>= 1) p += __shfl_xor(p, off);
      if (lane == 0) s1[wid * HEADS + h] = p;
    }
  }
}

// ---------------------------------------------------------------------------
// Phase 1: per-edge logits (E x 4), edge-parallel, float4.
// ---------------------------------------------------------------------------
__global__ __launch_bounds__(256) void edge_logits_kernel(
    const float* __restrict__ s_src, const float* __restrict__ s_dst,
    const int* __restrict__ src_idx, const int* __restrict__ dst_idx,
    float* __restrict__ logit, int n_edge) {
  int e = blockIdx.x * blockDim.x + threadIdx.x;
  if (e >= n_edge) return;
  int s = src_idx[e], d = dst_idx[e];
  float4 a = *(const float4*)&s_src[(size_t)s * HEADS];
  float4 b = *(const float4*)&s_dst[(size_t)d * HEADS];
  float4 v = make_float4(a.x + b.x, a.y + b.y, a.z + b.z, a.w + b.w);
  v.x = (v.x >= 0.f) ? v.x : 0.2f * v.x;
  v.y = (v.y >= 0.f) ? v.y : 0.2f * v.y;
  v.z = (v.z >= 0.f) ? v.z : 0.2f * v.z;
  v.w = (v.w >= 0.f) ? v.w : 0.2f * v.w;
  *(float4*)&logit[(size_t)e * HEADS] = v;
}

// ---------------------------------------------------------------------------
// Phase 2: segment softmax stats, one thread per dst node.
// ---------------------------------------------------------------------------
__global__ __launch_bounds__(256) void seg_softmax_kernel(
    const int* __restrict__ rs, float* __restrict__ logit,
    float* __restrict__ rden, int n_dst) {
  int i = blockIdx.x * blockDim.x + threadIdx.x;
  if (i >= n_dst) return;
  int e0 = rs[i], e1 = rs[i + 1];
  float4 m = make_float4(-INFINITY, -INFINITY, -INFINITY, -INFINITY);
  for (int e = e0; e < e1; ++e) {
    float4 lg = *(const float4*)&logit[(size_t)e * HEADS];
    m.x = fmaxf(m.x, lg.x); m.y = fmaxf(m.y, lg.y);
    m.z = fmaxf(m.z, lg.z); m.w = fmaxf(m.w, lg.w);
  }
  float4 den = make_float4(0.f, 0.f, 0.f, 0.f);
  for (int e = e0; e < e1; ++e) {
    float4 lg = *(const float4*)&logit[(size_t)e * HEADS];
    float4 w = make_float4(__expf(lg.x - m.x), __expf(lg.y - m.y),
                           __expf(lg.z - m.z), __expf(lg.w - m.w));
    den.x += w.x; den.y += w.y; den.z += w.z; den.w += w.w;
    *(float4*)&logit[(size_t)e * HEADS] = w;
  }
  float4 r;
  r.x = den.x > 0.f ? 1.f / den.x : 0.f;
  r.y = den.y > 0.f ? 1.f / den.y : 0.f;
  r.z = den.z > 0.f ? 1.f / den.z : 0.f;
  r.w = den.w > 0.f ? 1.f / den.w : 0.f;
  *(float4*)&rden[(size_t)i * HEADS] = r;
}

// ---------------------------------------------------------------------------
// Phase 3: weighted gather-sum. One wave per dst; lanes = 2 edge-slots x
// 32 dim-groups (float4). Optionally fuses s_out = out @ a_next^T.
// ---------------------------------------------------------------------------
#define ACC4(acc, wv, hv) \
  acc.x = fmaf(wv, hv.x, acc.x); acc.y = fmaf(wv, hv.y, acc.y); \
  acc.z = fmaf(wv, hv.z, acc.z); acc.w = fmaf(wv, hv.w, acc.w);

__global__ __launch_bounds__(256) void attend_sum_kernel(
    const float* __restrict__ h_src, const float* __restrict__ w4,
    const float* __restrict__ rden, const int* __restrict__ src_idx,
    const int* __restrict__ rs, float* __restrict__ out, int n_dst,
    const float* __restrict__ a_next, float* __restrict__ s_out) {
  int wid = (blockIdx.x * blockDim.x + threadIdx.x) >> 6;
  int lane = threadIdx.x & 63;
  if (wid >= n_dst) return;
  const int el = lane >> 5;
  const int dl = lane & 31;
  int e0 = rs[wid], e1 = rs[wid + 1];

  float4 acc0 = make_float4(0, 0, 0, 0), acc1 = acc0, acc2 = acc0, acc3 = acc0;

  int base = e0;
  for (; base + 4 <= e1; base += 4) {
    int eA = base + el, eB = base + 2 + el;
    int sA = src_idx[eA], sB = src_idx[eB];
    float4 hA = *(const float4*)&h_src[(size_t)sA * D_H + dl * 4];
    float4 hB = *(const float4*)&h_src[(size_t)sB * D_H + dl * 4];
    float4 wA = *(const float4*)&w4[(size_t)eA * HEADS];
    float4 wB = *(const float4*)&w4[(size_t)eB * HEADS];
    ACC4(acc0, wA.x, hA); ACC4(acc1, wA.y, hA);
    ACC4(acc2, wA.z, hA); ACC4(acc3, wA.w, hA);
    ACC4(acc0, wB.x, hB); ACC4(acc1, wB.y, hB);
    ACC4(acc2, wB.z, hB); ACC4(acc3, wB.w, hB);
  }
  for (; base < e1; base += 2) {
    int e = base + el;
    bool valid = e < e1;
    int ec = valid ? e : e1 - 1;
    int s = src_idx[ec];
    float4 hv = *(const float4*)&h_src[(size_t)s * D_H + dl * 4];
    float4 wv = *(const float4*)&w4[(size_t)ec * HEADS];
    if (!valid) wv = make_float4(0, 0, 0, 0);
    ACC4(acc0, wv.x, hv); ACC4(acc1, wv.y, hv);
    ACC4(acc2, wv.z, hv); ACC4(acc3, wv.w, hv);
  }

#define MRG(a) \
  a.x += __shfl_xor(a.x, 32); a.y += __shfl_xor(a.y, 32); \
  a.z += __shfl_xor(a.z, 32); a.w += __shfl_xor(a.w, 32);
  MRG(acc0) MRG(acc1) MRG(acc2) MRG(acc3)
#undef MRG

  float4 r = *(const float4*)&rden[(size_t)wid * HEADS];
#define ELU4(a, rr) \
  a.x *= rr; a.y *= rr; a.z *= rr; a.w *= rr; \
  a.x = (a.x > 0.f) ? a.x : expm1f(a.x); \
  a.y = (a.y > 0.f) ? a.y : expm1f(a.y); \
  a.z = (a.z > 0.f) ? a.z : expm1f(a.z); \
  a.w = (a.w > 0.f) ? a.w : expm1f(a.w);
  ELU4(acc0, r.x) ELU4(acc1, r.y) ELU4(acc2, r.z) ELU4(acc3, r.w)
#undef ELU4

  float4 o = make_float4(0.25f * (acc0.x + acc1.x + acc2.x + acc3.x),
                         0.25f * (acc0.y + acc1.y + acc2.y + acc3.y),
                         0.25f * (acc0.z + acc1.z + acc2.z + acc3.z),
                         0.25f * (acc0.w + acc1.w + acc2.w + acc3.w));
  if (el == 0) *(float4*)&out[(size_t)wid * D_H + dl * 4] = o;

  if (s_out) {
#pragma unroll
    for (int h = 0; h < HEADS; ++h) {
      const float* ah = &a_next[h * D_H + dl * 4];
      float p = o.x * ah[0] + o.y * ah[1] + o.z * ah[2] + o.w * ah[3];
#pragma unroll
      for (int off = 16; off; off >>= 1) p += __shfl_xor(p, off);
      if (lane == 0) s_out[wid * HEADS + h] = p;
    }
  }
}
#undef ACC4

// ---------------------------------------------------------------------------
extern "C" void kernel_launch(void* const* d_in, const int* in_sizes, int n_in,
                              void* d_out, int out_size, void* d_ws, size_t ws_size,
                              hipStream_t stream) {
  const float* h_user     = (const float*)d_in[0];
  const float* h_item     = (const float*)d_in[1];
  const float* w_user     = (const float*)d_in[2];
  const float* b_user     = (const float*)d_in[3];
  const float* w_item     = (const float*)d_in[4];
  const float* b_item     = (const float*)d_in[5];
  const float* a_user_src = (const float*)d_in[6];
  const float* a_user_dst = (const float*)d_in[7];
  const float* a_item_src = (const float*)d_in[8];
  const float* a_item_dst = (const float*)d_in[9];
  const int* i2u_src = (const int*)d_in[10];
  const int* i2u_dst = (const int*)d_in[11];
  const int* u2i_src = (const int*)d_in[12];
  const int* u2i_dst = (const int*)d_in[13];

  float* out_user = (float*)d_out;                       // hu_new (N_USER,128)
  float* out_item = out_user + (size_t)N_USER * D_H;     // hi_new (N_ITEM,128)

  // workspace layout
  float* hu      = (float*)d_ws;                         // (N_USER,128) 51.2MB
  float* hi      = hu + (size_t)N_USER * D_H;            // (N_ITEM,128)
  float* s_i_src = hi + (size_t)N_ITEM * D_H;            // (N_ITEM,4)
  float* s_i_dst = s_i_src + (size_t)N_ITEM * HEADS;     // (N_ITEM,4)
  float* s_u_dst = s_i_dst + (size_t)N_ITEM * HEADS;     // (N_USER,4)
  float* s_un    = s_u_dst + (size_t)N_USER * HEADS;     // (N_USER,4)
  int* user_rs = (int*)(s_un + (size_t)N_USER * HEADS);  // N_USER+1
  int* item_rs = user_rs + (N_USER + 1);                 // N_ITEM+1
  // pre-transposed/permuted W (bf16 hi/lo), 4 x 64KB, 16B aligned
  unsigned short* wtu_hi = (unsigned short*)
      (((uintptr_t)(item_rs + N_ITEM + 1) + 15) & ~(uintptr_t)15);
  unsigned short* wtu_lo = wtu_hi + (size_t)D_IN * D_H;
  unsigned short* wti_hi = wtu_lo + (size_t)D_IN * D_H;
  unsigned short* wti_lo = wti_hi + (size_t)D_IN * D_H;
  // hu is dead after scores_kernel -> alias edge buffers into it
  float* logit  = hu;                                    // (E,4) 12.8MB
  float* rden_u = hu + (size_t)N_EDGE * HEADS;           // (N_USER,4)
  float* rden_i = rden_u + (size_t)N_USER * HEADS;       // (N_ITEM,4)

  // CSR offsets from the sorted dst arrays
  hipLaunchKernelGGL(row_offsets_kernel, dim3((N_USER + 1 + 255) / 256), dim3(256), 0,
                     stream, i2u_dst, N_EDGE, user_rs, N_USER);
  hipLaunchKernelGGL(row_offsets_kernel, dim3((N_ITEM + 1 + 255) / 256), dim3(256), 0,
                     stream, u2i_dst, N_EDGE, item_rs, N_ITEM);

  // W prep + projections (split-bf16 MFMA)
  hipLaunchKernelGGL(wt_prep_kernel, dim3(D_IN * D_H / 256), dim3(256), 0, stream,
                     w_user, wtu_hi, wtu_lo);
  hipLaunchKernelGGL(wt_prep_kernel, dim3(D_IN * D_H / 256), dim3(256), 0, stream,
                     w_item, wti_hi, wti_lo);
  hipLaunchKernelGGL(gemm_mfma_kernel, dim3((N_USER + 127) / 128), dim3(256), 0, stream,
                     h_user, wtu_hi, wtu_lo, b_user, hu, N_USER);
  hipLaunchKernelGGL(gemm_mfma_kernel, dim3((N_ITEM + 127) / 128), dim3(256), 0, stream,
                     h_item, wti_hi, wti_lo, b_item, hi, N_ITEM);

  // per-node attention scores
  hipLaunchKernelGGL(scores_kernel, dim3(N_ITEM / 4), dim3(256), 0, stream,
                     hi, N_ITEM, a_user_src, s_i_src, a_item_dst, s_i_dst);
  hipLaunchKernelGGL(scores_kernel, dim3(N_USER / 4), dim3(256), 0, stream,
                     hu, N_USER, a_user_dst, s_u_dst, (const float*)nullptr, (float*)nullptr);

  // ---- layer 1: items -> users ----
  hipLaunchKernelGGL(edge_logits_kernel, dim3((N_EDGE + 255) / 256), dim3(256), 0, stream,
                     s_i_src, s_u_dst, i2u_src, i2u_dst, logit, N_EDGE);
  hipLaunchKernelGGL(seg_softmax_kernel, dim3((N_USER + 255) / 256), dim3(256), 0, stream,
                     user_rs, logit, rden_u, N_USER);
  hipLaunchKernelGGL(attend_sum_kernel, dim3((N_USER + 3) / 4), dim3(256), 0, stream,
                     hi, logit, rden_u, i2u_src, user_rs, out_user, N_USER,
                     a_item_src, s_un);

  // ---- layer 2: updated users -> items ----
  hipLaunchKernelGGL(edge_logits_kernel, dim3((N_EDGE + 255) / 256), dim3(256), 0, stream,
                     s_un, s_i_dst, u2i_src, u2i_dst, logit, N_EDGE);
  hipLaunchKernelGGL(seg_softmax_kernel, dim3((N_ITEM + 255) / 256), dim3(256), 0, stream,
                     item_rs, logit, rden_i, N_ITEM);
  hipLaunchKernelGGL(attend_sum_kernel, dim3((N_ITEM + 3) / 4), dim3(256), 0, stream,
                     out_user, logit, rden_i, u2i_src, item_rs, out_item, N_ITEM,
                     (const float*)nullptr, (float*)nullptr);
}

// Round 5
// 357.508 us; speedup vs baseline: 1.2666x; 1.1628x over previous
//
#include <hip/hip_runtime.h>
#include <math.h>

#define N_USER 100000
#define N_ITEM 50000
#define N_EDGE 800000
#define D_IN 256
#define D_H 128
#define HEADS 4

typedef __attribute__((ext_vector_type(8))) short short8v;   // 8 bf16 (4 VGPR)
typedef __attribute__((ext_vector_type(4))) float f32x4;     // 4 fp32

__device__ __forceinline__ unsigned short f2bf(float x) {    // RNE f32->bf16
  unsigned u = __float_as_uint(x);
  return (unsigned short)((u + 0x7FFFu + ((u >> 16) & 1u)) >> 16);
}
__device__ __forceinline__ float bf2f(unsigned short h) {
  return __uint_as_float((unsigned)h << 16);
}
__device__ __forceinline__ f32x4 splat4(float x) { return (f32x4){x, x, x, x}; }

// ---------------------------------------------------------------------------
// CSR row offsets, edge-parallel: thread e writes rs[i]=e for all i in
// (dst[e-1], dst[e]]; thread 0 covers [0, dst[0]]; last thread writes tail.
// Each rs[i] written exactly once -> deterministic.
// ---------------------------------------------------------------------------
__global__ void row_offsets_kernel(const int* __restrict__ dst, int n_edge,
                                   int* __restrict__ rs, int n_dst) {
  int e = blockIdx.x * blockDim.x + threadIdx.x;
  if (e >= n_edge) return;
  int d = dst[e];
  int dprev = (e == 0) ? -1 : dst[e - 1];
  for (int i = dprev + 1; i <= d; ++i) rs[i] = e;
  if (e == n_edge - 1)
    for (int i = d + 1; i <= n_dst; ++i) rs[i] = n_edge;
}

// ---------------------------------------------------------------------------
// One-time W prep: W[256][128] fp32 -> Wt_hi/Wt_lo[128][256] bf16, k permuted
// to the MFMA fragment slot order (see gemm kernel).
// ---------------------------------------------------------------------------
__global__ __launch_bounds__(256) void wt_prep_kernel(
    const float* __restrict__ W, unsigned short* __restrict__ WtHi,
    unsigned short* __restrict__ WtLo) {
  int tid = blockIdx.x * blockDim.x + threadIdx.x;
  if (tid >= D_IN * D_H) return;
  int n = tid & 127, k = tid >> 7;
  float x = W[(size_t)k * D_H + n];
  unsigned short h = f2bf(x);
  unsigned short l = f2bf(x - bf2f(h));
  int kk = k & 31, kbase = k & ~31;
  int pos = (kk < 16) ? ((kk >> 2) * 8 + (kk & 3))
                      : (((kk - 16) >> 2) * 8 + 4 + (kk & 3));
  WtHi[(size_t)n * D_IN + kbase + pos] = h;
  WtLo[(size_t)n * D_IN + kbase + pos] = l;
}

// ---------------------------------------------------------------------------
// C[M,128] = A[M,256] @ W[256,128] + bias via split-bf16 MFMA
// (Ah*Wh + Ah*Wl + Al*Wh, fp32 accumulate).
// ---------------------------------------------------------------------------
__global__ __launch_bounds__(256) void gemm_mfma_kernel(
    const float* __restrict__ A, const unsigned short* __restrict__ WtHi,
    const unsigned short* __restrict__ WtLo, const float* __restrict__ bias,
    float* __restrict__ C, int M) {
  __shared__ unsigned short Ah[128][32], Al[128][32];
  __shared__ unsigned short Bh[128][32], Bl[128][32];
  const int t = threadIdx.x;
  const int wave = t >> 6, lane = t & 63;
  const int l15 = lane & 15, kb = lane >> 4;
  const int m0 = blockIdx.x * 128;

  f32x4 acc[2][8];
#pragma unroll
  for (int mf = 0; mf < 2; ++mf)
#pragma unroll
    for (int nf = 0; nf < 8; ++nf) acc[mf][nf] = (f32x4){0.f, 0.f, 0.f, 0.f};

  for (int k0 = 0; k0 < D_IN; k0 += 32) {
#pragma unroll
    for (int i = 0; i < 4; ++i) {
      int idx = t + i * 256;
      int row = idx >> 3, c = idx & 7;
      float4 av = make_float4(0.f, 0.f, 0.f, 0.f);
      if (m0 + row < M) av = *(const float4*)&A[(size_t)(m0 + row) * D_IN + k0 + c * 4];
      ushort4 hv, lv;
      hv.x = f2bf(av.x); lv.x = f2bf(av.x - bf2f(hv.x));
      hv.y = f2bf(av.y); lv.y = f2bf(av.y - bf2f(hv.y));
      hv.z = f2bf(av.z); lv.z = f2bf(av.z - bf2f(hv.z));
      hv.w = f2bf(av.w); lv.w = f2bf(av.w - bf2f(hv.w));
      int base = (c < 4) ? c * 8 : (c - 4) * 8 + 4;
      *(ushort4*)&Ah[row][base] = hv;
      *(ushort4*)&Al[row][base] = lv;
    }
#pragma unroll
    for (int i = 0; i < 2; ++i) {
      int idx = t + i * 256;
      int row = idx >> 2, ch = idx & 3;
      *(uint4*)&Bh[row][ch * 8] = *(const uint4*)&WtHi[(size_t)row * D_IN + k0 + ch * 8];
      *(uint4*)&Bl[row][ch * 8] = *(const uint4*)&WtLo[(size_t)row * D_IN + k0 + ch * 8];
    }
    __syncthreads();

    short8v ah[2], al[2];
#pragma unroll
    for (int mf = 0; mf < 2; ++mf) {
      ah[mf] = *(const short8v*)&Ah[wave * 32 + mf * 16 + l15][kb * 8];
      al[mf] = *(const short8v*)&Al[wave * 32 + mf * 16 + l15][kb * 8];
    }
#pragma unroll
    for (int nf = 0; nf < 8; ++nf) {
      short8v bh = *(const short8v*)&Bh[nf * 16 + l15][kb * 8];
      short8v bl = *(const short8v*)&Bl[nf * 16 + l15][kb * 8];
#pragma unroll
      for (int mf = 0; mf < 2; ++mf) {
        acc[mf][nf] = __builtin_amdgcn_mfma_f32_16x16x32_bf16(ah[mf], bh, acc[mf][nf], 0, 0, 0);
        acc[mf][nf] = __builtin_amdgcn_mfma_f32_16x16x32_bf16(ah[mf], bl, acc[mf][nf], 0, 0, 0);
        acc[mf][nf] = __builtin_amdgcn_mfma_f32_16x16x32_bf16(al[mf], bh, acc[mf][nf], 0, 0, 0);
      }
    }
    __syncthreads();
  }

#pragma unroll
  for (int nf = 0; nf < 8; ++nf) {
    float bv = bias[nf * 16 + l15];
#pragma unroll
    for (int mf = 0; mf < 2; ++mf) {
#pragma unroll
      for (int r = 0; r < 4; ++r) {
        int grow = m0 + wave * 32 + mf * 16 + kb * 4 + r;
        if (grow < M) C[(size_t)grow * D_H + nf * 16 + l15] = acc[mf][nf][r] + bv;
      }
    }
  }
}

// ---------------------------------------------------------------------------
// s[n,4] = C[n,128] @ a[4,128]^T  (one wave per row; optional second a)
// ---------------------------------------------------------------------------
__global__ __launch_bounds__(256) void scores_kernel(
    const float* __restrict__ C, int n,
    const float* __restrict__ a0, float* __restrict__ s0,
    const float* __restrict__ a1, float* __restrict__ s1) {
  int wid = (blockIdx.x * blockDim.x + threadIdx.x) >> 6;
  int lane = threadIdx.x & 63;
  if (wid >= n) return;
  float2 v = *(const float2*)&C[(size_t)wid * D_H + lane * 2];
#pragma unroll
  for (int h = 0; h < HEADS; ++h) {
    float p = v.x * a0[h * D_H + lane * 2] + v.y * a0[h * D_H + lane * 2 + 1];
#pragma unroll
    for (int off = 32; off; off >>= 1) p += __shfl_xor(p, off);
    if (lane == 0) s0[wid * HEADS + h] = p;
  }
  if (a1) {
#pragma unroll
    for (int h = 0; h < HEADS; ++h) {
      float p = v.x * a1[h * D_H + lane * 2] + v.y * a1[h * D_H + lane * 2 + 1];
#pragma unroll
      for (int off = 32; off; off >>= 1) p += __shfl_xor(p, off);
      if (lane == 0) s1[wid * HEADS + h] = p;
    }
  }
}

// ---------------------------------------------------------------------------
// Phase 1: per-edge UNNORMALIZED weights w = exp(leaky_relu(s_src+s_dst)).
// No max-shift: softmax is shift-invariant; |logit| ~ O(10), exp safe in f32.
// ---------------------------------------------------------------------------
__global__ __launch_bounds__(256) void edge_w_kernel(
    const float* __restrict__ s_src, const float* __restrict__ s_dst,
    const int* __restrict__ src_idx, const int* __restrict__ dst_idx,
    float* __restrict__ wout, int n_edge) {
  int e = blockIdx.x * blockDim.x + threadIdx.x;
  if (e >= n_edge) return;
  int s = src_idx[e], d = dst_idx[e];
  f32x4 a = *(const f32x4*)&s_src[(size_t)s * HEADS];
  f32x4 b = *(const f32x4*)&s_dst[(size_t)d * HEADS];
  f32x4 v = a + b;
  v.x = (v.x >= 0.f) ? v.x : 0.2f * v.x;
  v.y = (v.y >= 0.f) ? v.y : 0.2f * v.y;
  v.z = (v.z >= 0.f) ? v.z : 0.2f * v.z;
  v.w = (v.w >= 0.f) ? v.w : 0.2f * v.w;
  f32x4 w = {__expf(v.x), __expf(v.y), __expf(v.z), __expf(v.w)};
  *(f32x4*)&wout[(size_t)e * HEADS] = w;
}

// ---------------------------------------------------------------------------
// Phase 2: weighted gather-sum + in-loop denominator. One wave per dst;
// lanes = 2 edge-slots x 32 dim-groups (float4). Packed f32x4 math
// (v_pk_fma_f32). Epilogue: slot-merge, 1/den scale, elu, head-mean;
// optionally fuses s_out = out @ a_next^T.
// ---------------------------------------------------------------------------
__global__ __launch_bounds__(256) void attend_sum_kernel(
    const float* __restrict__ h_src, const float* __restrict__ w4,
    const int* __restrict__ src_idx, const int* __restrict__ rs,
    float* __restrict__ out, int n_dst,
    const float* __restrict__ a_next, float* __restrict__ s_out) {
  int wid = (blockIdx.x * blockDim.x + threadIdx.x) >> 6;
  int lane = threadIdx.x & 63;
  if (wid >= n_dst) return;
  const int el = lane >> 5;        // edge slot 0/1
  const int dl = lane & 31;        // dim group: dims [dl*4, dl*4+4)
  int e0 = rs[wid], e1 = rs[wid + 1];

  f32x4 acc0 = {0, 0, 0, 0}, acc1 = acc0, acc2 = acc0, acc3 = acc0;
  f32x4 den = {0, 0, 0, 0};

  int base = e0;
  for (; base + 4 <= e1; base += 4) {          // 4 edges/iter, 2 per slot
    int eA = base + el, eB = base + 2 + el;
    int sA = src_idx[eA], sB = src_idx[eB];
    f32x4 hA = *(const f32x4*)&h_src[(size_t)sA * D_H + dl * 4];
    f32x4 hB = *(const f32x4*)&h_src[(size_t)sB * D_H + dl * 4];
    f32x4 wA = *(const f32x4*)&w4[(size_t)eA * HEADS];
    f32x4 wB = *(const f32x4*)&w4[(size_t)eB * HEADS];
    den += wA; den += wB;
    acc0 = __builtin_elementwise_fma(splat4(wA.x), hA, acc0);
    acc1 = __builtin_elementwise_fma(splat4(wA.y), hA, acc1);
    acc2 = __builtin_elementwise_fma(splat4(wA.z), hA, acc2);
    acc3 = __builtin_elementwise_fma(splat4(wA.w), hA, acc3);
    acc0 = __builtin_elementwise_fma(splat4(wB.x), hB, acc0);
    acc1 = __builtin_elementwise_fma(splat4(wB.y), hB, acc1);
    acc2 = __builtin_elementwise_fma(splat4(wB.z), hB, acc2);
    acc3 = __builtin_elementwise_fma(splat4(wB.w), hB, acc3);
  }
  for (; base < e1; base += 2) {               // tail: up to 3 edges
    int e = base + el;
    bool valid = e < e1;
    int ec = valid ? e : e1 - 1;
    int s = src_idx[ec];
    f32x4 hv = *(const f32x4*)&h_src[(size_t)s * D_H + dl * 4];
    f32x4 wv = *(const f32x4*)&w4[(size_t)ec * HEADS];
    if (!valid) wv = (f32x4){0, 0, 0, 0};
    den += wv;
    acc0 = __builtin_elementwise_fma(splat4(wv.x), hv, acc0);
    acc1 = __builtin_elementwise_fma(splat4(wv.y), hv, acc1);
    acc2 = __builtin_elementwise_fma(splat4(wv.z), hv, acc2);
    acc3 = __builtin_elementwise_fma(splat4(wv.w), hv, acc3);
  }

  // merge the two edge-slots (xor 32): both halves end with full sums
#define MRG(a) \
  a.x += __shfl_xor(a.x, 32); a.y += __shfl_xor(a.y, 32); \
  a.z += __shfl_xor(a.z, 32); a.w += __shfl_xor(a.w, 32);
  MRG(acc0) MRG(acc1) MRG(acc2) MRG(acc3) MRG(den)
#undef MRG

  float r0 = den.x > 0.f ? 1.f / den.x : 0.f;
  float r1 = den.y > 0.f ? 1.f / den.y : 0.f;
  float r2 = den.z > 0.f ? 1.f / den.z : 0.f;
  float r3 = den.w > 0.f ? 1.f / den.w : 0.f;
  acc0 *= splat4(r0); acc1 *= splat4(r1); acc2 *= splat4(r2); acc3 *= splat4(r3);
#define ELU4(a) \
  a.x = (a.x > 0.f) ? a.x : (__expf(a.x) - 1.f); \
  a.y = (a.y > 0.f) ? a.y : (__expf(a.y) - 1.f); \
  a.z = (a.z > 0.f) ? a.z : (__expf(a.z) - 1.f); \
  a.w = (a.w > 0.f) ? a.w : (__expf(a.w) - 1.f);
  ELU4(acc0) ELU4(acc1) ELU4(acc2) ELU4(acc3)
#undef ELU4

  f32x4 o = (acc0 + acc1 + acc2 + acc3) * splat4(0.25f);
  if (el == 0) *(f32x4*)&out[(size_t)wid * D_H + dl * 4] = o;

  if (s_out) {  // fused next-layer src scores
#pragma unroll
    for (int h = 0; h < HEADS; ++h) {
      const float* ah = &a_next[h * D_H + dl * 4];
      float p = o.x * ah[0] + o.y * ah[1] + o.z * ah[2] + o.w * ah[3];
#pragma unroll
      for (int off = 16; off; off >>= 1) p += __shfl_xor(p, off);
      if (lane == 0) s_out[wid * HEADS + h] = p;
    }
  }
}

// ---------------------------------------------------------------------------
extern "C" void kernel_launch(void* const* d_in, const int* in_sizes, int n_in,
                              void* d_out, int out_size, void* d_ws, size_t ws_size,
                              hipStream_t stream) {
  const float* h_user     = (const float*)d_in[0];
  const float* h_item     = (const float*)d_in[1];
  const float* w_user     = (const float*)d_in[2];
  const float* b_user     = (const float*)d_in[3];
  const float* w_item     = (const float*)d_in[4];
  const float* b_item     = (const float*)d_in[5];
  const float* a_user_src = (const float*)d_in[6];
  const float* a_user_dst = (const float*)d_in[7];
  const float* a_item_src = (const float*)d_in[8];
  const float* a_item_dst = (const float*)d_in[9];
  const int* i2u_src = (const int*)d_in[10];
  const int* i2u_dst = (const int*)d_in[11];
  const int* u2i_src = (const int*)d_in[12];
  const int* u2i_dst = (const int*)d_in[13];

  float* out_user = (float*)d_out;                       // hu_new (N_USER,128)
  float* out_item = out_user + (size_t)N_USER * D_H;     // hi_new (N_ITEM,128)

  // workspace layout
  float* hu      = (float*)d_ws;                         // (N_USER,128) 51.2MB
  float* hi      = hu + (size_t)N_USER * D_H;            // (N_ITEM,128)
  float* s_i_src = hi + (size_t)N_ITEM * D_H;            // (N_ITEM,4)
  float* s_i_dst = s_i_src + (size_t)N_ITEM * HEADS;     // (N_ITEM,4)
  float* s_u_dst = s_i_dst + (size_t)N_ITEM * HEADS;     // (N_USER,4)
  float* s_un    = s_u_dst + (size_t)N_USER * HEADS;     // (N_USER,4)
  int* user_rs = (int*)(s_un + (size_t)N_USER * HEADS);  // N_USER+1
  int* item_rs = user_rs + (N_USER + 1);                 // N_ITEM+1
  unsigned short* wtu_hi = (unsigned short*)
      (((uintptr_t)(item_rs + N_ITEM + 1) + 15) & ~(uintptr_t)15);
  unsigned short* wtu_lo = wtu_hi + (size_t)D_IN * D_H;
  unsigned short* wti_hi = wtu_lo + (size_t)D_IN * D_H;
  unsigned short* wti_lo = wti_hi + (size_t)D_IN * D_H;
  // hu is dead after scores_kernel -> alias edge weight buffer into it
  float* wbuf = hu;                                      // (E,4) 12.8MB

  // CSR offsets (edge-parallel run writes)
  hipLaunchKernelGGL(row_offsets_kernel, dim3((N_EDGE + 255) / 256), dim3(256), 0,
                     stream, i2u_dst, N_EDGE, user_rs, N_USER);
  hipLaunchKernelGGL(row_offsets_kernel, dim3((N_EDGE + 255) / 256), dim3(256), 0,
                     stream, u2i_dst, N_EDGE, item_rs, N_ITEM);

  // W prep + projections (split-bf16 MFMA)
  hipLaunchKernelGGL(wt_prep_kernel, dim3(D_IN * D_H / 256), dim3(256), 0, stream,
                     w_user, wtu_hi, wtu_lo);
  hipLaunchKernelGGL(wt_prep_kernel, dim3(D_IN * D_H / 256), dim3(256), 0, stream,
                     w_item, wti_hi, wti_lo);
  hipLaunchKernelGGL(gemm_mfma_kernel, dim3((N_USER + 127) / 128), dim3(256), 0, stream,
                     h_user, wtu_hi, wtu_lo, b_user, hu, N_USER);
  hipLaunchKernelGGL(gemm_mfma_kernel, dim3((N_ITEM + 127) / 128), dim3(256), 0, stream,
                     h_item, wti_hi, wti_lo, b_item, hi, N_ITEM);

  // per-node attention scores
  hipLaunchKernelGGL(scores_kernel, dim3(N_ITEM / 4), dim3(256), 0, stream,
                     hi, N_ITEM, a_user_src, s_i_src, a_item_dst, s_i_dst);
  hipLaunchKernelGGL(scores_kernel, dim3(N_USER / 4), dim3(256), 0, stream,
                     hu, N_USER, a_user_dst, s_u_dst, (const float*)nullptr, (float*)nullptr);

  // ---- layer 1: items -> users ----
  hipLaunchKernelGGL(edge_w_kernel, dim3((N_EDGE + 255) / 256), dim3(256), 0, stream,
                     s_i_src, s_u_dst, i2u_src, i2u_dst, wbuf, N_EDGE);
  hipLaunchKernelGGL(attend_sum_kernel, dim3((N_USER + 3) / 4), dim3(256), 0, stream,
                     hi, wbuf, i2u_src, user_rs, out_user, N_USER,
                     a_item_src, s_un);

  // ---- layer 2: updated users -> items ----
  hipLaunchKernelGGL(edge_w_kernel, dim3((N_EDGE + 255) / 256), dim3(256), 0, stream,
                     s_un, s_i_dst, u2i_src, u2i_dst, wbuf, N_EDGE);
  hipLaunchKernelGGL(attend_sum_kernel, dim3((N_ITEM + 3) / 4), dim3(256), 0, stream,
                     out_user, wbuf, u2i_src, item_rs, out_item, N_ITEM,
                     (const float*)nullptr, (float*)nullptr);
}